// Round 14
// baseline (624.314 us; speedup 1.0000x reference)
//
#include <hip/hip_runtime.h>
#include <float.h>

#define D_DIM 768
#define K_DIM 500
#define NDT   24          // 768 / 32 D-tiles
#define BM    64          // rows per block
#define NTH   256
#define PB_STRIDE 100352  // padded per-half partial stride (rows)

typedef _Float16 f16x8 __attribute__((ext_vector_type(8)));
typedef float    f32x4 __attribute__((ext_vector_type(4)));

// ws layout:
//   0        : cnorm   float[512]                 (2 KB)
//   4096     : partial double[16*512]             (64 KB)
//   131072   : BpH     _Float16[24*512*32]        (768 KB)
//   917504   : BpL     _Float16[24*512*32]        (768 KB)
//   1703936  : pbv     float[2*PB_STRIDE]         (~800 KB)
//   2506752  : pbi     int[2*PB_STRIDE]           (~800 KB)

// ---------------- cnorm prep (exact, fp64) ----------------
__global__ void cnorm_partial_kernel(const float* __restrict__ C,
                                     double* __restrict__ partial, int K) {
    const int k = threadIdx.x;
    const int w = blockIdx.x;    // 0..15
    double s = 0.0;
    if (k < K) {
        const int d0 = w * (D_DIM / 16);
        for (int d = d0; d < d0 + (D_DIM / 16); ++d) {
            const float c = C[(size_t)d * K + k];
            s = fma((double)c, (double)c, s);
        }
    }
    partial[w * 512 + k] = s;
}

__global__ void cnorm_finish_kernel(const double* __restrict__ partial,
                                    float* __restrict__ cnorm, int K) {
    const int k = threadIdx.x;
    if (k < K) {
        double s = 0.0;
        for (int w = 0; w < 16; ++w) s += partial[w * 512 + k];
        cnorm[k] = (float)s;
    } else {
        cnorm[k] = FLT_MAX;
    }
}

// ---------------- pack C into fragment-ready f16 hi/lo planes ----------------
__global__ void packB_kernel(const float* __restrict__ C,
                             _Float16* __restrict__ BpH,
                             _Float16* __restrict__ BpL) {
    const int idx = blockIdx.x * 256 + threadIdx.x;   // 0..12287
    const int col = idx & 511;
    const int dt  = idx >> 9;                         // 0..23
    f16x8 h[4], l[4];
    #pragma unroll
    for (int c = 0; c < 4; ++c)
        #pragma unroll
        for (int j = 0; j < 8; ++j) {
            const int k = c * 8 + j;
            const float v = (col < K_DIM)
                          ? C[(size_t)(dt * 32 + k) * K_DIM + col] : 0.0f;
            const _Float16 hh = (_Float16)v;
            h[c][j] = hh;
            l[c][j] = (_Float16)(v - (float)hh);
        }
    f16x8* dH = (f16x8*)(BpH + ((size_t)dt * 512 + col) * 32);
    f16x8* dL = (f16x8*)(BpL + ((size_t)dt * 512 + col) * 32);
    #pragma unroll
    for (int c = 0; c < 4; ++c) { dH[c] = h[c]; dL[c] = l[c]; }
}

// ---- main: col-split fp16-split MFMA, B reg-dbuf + soft barrier pipeline ----
__launch_bounds__(NTH, 3)
__global__ void assign_kernel(const float* __restrict__ feat,
                              const _Float16* __restrict__ BpH,
                              const _Float16* __restrict__ BpL,
                              const float* __restrict__ cnorm,
                              float* __restrict__ pbv,
                              int* __restrict__ pbi,
                              int T) {
    // A tiles double-buffered: 2 planes x 2 bufs x 4KB = 16KB
    __shared__ __align__(16) _Float16 AsH[2][BM * 32];
    __shared__ __align__(16) _Float16 AsL[2][BM * 32];
    __shared__ float red_v[BM * 4];
    __shared__ int   red_i[BM * 4];

    const int tid  = threadIdx.x;
    const int wn   = tid >> 6;    // 0..3 (64-col slice)
    const int lane = tid & 63;
    const int l15  = lane & 15;
    const int kg   = lane >> 4;   // 0..3 (k-group)
    const int bid  = blockIdx.x;
    const int half = bid & 1;     // col half: 0 -> cols 0..255, 1 -> 256..511
    const int R0   = (bid >> 1) * BM;

    // A staging map: 4 threads per row, 8 floats each
    const int ar = tid >> 2;            // 0..63
    const int ac = (tid & 3) << 3;      // 0,8,16,24
    const bool arow_ok = (R0 + ar) < T;
    const float* fptr = feat + (size_t)(R0 + ar) * D_DIM + ac;
    const int asl = ((ac >> 3) + (ar >> 1)) & 3;      // slot swizzle for write

    // B fragment base: global col = half*256 + wn*64 + l15, k-chunk kg
    const int colbase = half * 256 + wn * 64 + l15;
    const _Float16* bpH = BpH + (size_t)colbase * 32 + kg * 8;
    const _Float16* bpL = BpL + (size_t)colbase * 32 + kg * 8;

    f32x4 acc[4][4];
    #pragma unroll
    for (int m = 0; m < 4; ++m)
        #pragma unroll
        for (int n = 0; n < 4; ++n) acc[m][n] = (f32x4){0.f, 0.f, 0.f, 0.f};

#define CVT_STORE(V0, V1, BUF) do {                                            \
    const float fa[8] = {(V0).x, (V0).y, (V0).z, (V0).w,                       \
                         (V1).x, (V1).y, (V1).z, (V1).w};                      \
    f16x8 h, l;                                                                \
    _Pragma("unroll")                                                          \
    for (int j = 0; j < 8; ++j) {                                              \
        const _Float16 hh = (_Float16)fa[j];                                   \
        h[j] = hh; l[j] = (_Float16)(fa[j] - (float)hh);                       \
    }                                                                          \
    ((f16x8*)AsH[BUF])[ar * 4 + asl] = h;                                      \
    ((f16x8*)AsL[BUF])[ar * 4 + asl] = l;                                      \
} while (0)

// lgkmcnt-only barrier: orders the LDS double-buffer across waves WITHOUT
// draining vmcnt -> the B(dt+1)/rawA register prefetch survives the barrier.
#define SOFT_BARRIER() do {                                                    \
    asm volatile("s_waitcnt lgkmcnt(0)" ::: "memory");                         \
    __builtin_amdgcn_s_barrier();                                              \
} while (0)

// One dt. BCH/BCL: B frags for THIS dt (prefetched last iteration -> the MFMA
// cluster's vmcnt wait is already satisfied). BNH/BNL receive B(dt+1).
// CUR0/CUR1: raw A for dt+1 (consumed by CVT here). NXT0/NXT1 receive dt+2.
#define BODY(DT, BCH, BCL, BNH, BNL, CUR0, CUR1, NXT0, NXT1) do {              \
    const int cur = (DT) & 1;                                                  \
    /* issue B(dt+1) loads: retire during the NEXT ~1500cyc iteration */       \
    if ((DT) + 1 < NDT) {                                                      \
        const size_t bo1 = (size_t)((DT) + 1) * 16384;                         \
        _Pragma("unroll")                                                      \
        for (int nh = 0; nh < 4; ++nh) {                                       \
            BNH[nh] = *(const f16x8*)(bpH + bo1 + nh * 512);                   \
            BNL[nh] = *(const f16x8*)(bpL + bo1 + nh * 512);                   \
        }                                                                      \
    }                                                                          \
    /* issue raw A for dt+2 */                                                 \
    if ((DT) + 2 < NDT && arow_ok) {                                           \
        const float* p = fptr + ((DT) + 2) * 32;                               \
        NXT0 = *(const float4*)(p);                                            \
        NXT1 = *(const float4*)(p + 4);                                        \
    }                                                                          \
    /* A frags read per 2-m group (16 live frag regs, not 32) + MFMA */        \
    _Pragma("unroll")                                                          \
    for (int mg = 0; mg < 2; ++mg) {                                           \
        f16x8 aH[2], aL[2];                                                    \
        _Pragma("unroll")                                                      \
        for (int mm = 0; mm < 2; ++mm) {                                       \
            const int row = (mg * 2 + mm) * 16 + l15;                          \
            const int sl  = (kg + (row >> 1)) & 3;                             \
            aH[mm] = ((const f16x8*)AsH[cur])[row * 4 + sl];                   \
            aL[mm] = ((const f16x8*)AsL[cur])[row * 4 + sl];                   \
        }                                                                      \
        __builtin_amdgcn_s_setprio(1);                                         \
        _Pragma("unroll")                                                      \
        for (int mm = 0; mm < 2; ++mm) {                                       \
            const int m = mg * 2 + mm;                                         \
            _Pragma("unroll")                                                  \
            for (int nh = 0; nh < 4; ++nh) {                                   \
                f32x4 a = acc[m][nh];                                          \
                a = __builtin_amdgcn_mfma_f32_16x16x32_f16(aH[mm], BCH[nh], a, 0, 0, 0); \
                a = __builtin_amdgcn_mfma_f32_16x16x32_f16(aL[mm], BCH[nh], a, 0, 0, 0); \
                a = __builtin_amdgcn_mfma_f32_16x16x32_f16(aH[mm], BCL[nh], a, 0, 0, 0); \
                acc[m][nh] = a;                                                \
            }                                                                  \
        }                                                                      \
        __builtin_amdgcn_s_setprio(0);                                         \
    }                                                                          \
    /* stage dt+1 tile (CUR was loaded a full iteration ago -> no stall) */    \
    if ((DT) + 1 < NDT) {                                                      \
        CVT_STORE(CUR0, CUR1, cur ^ 1);                                        \
    }                                                                          \
    SOFT_BARRIER();                                                            \
} while (0)

    // ---- prologue: stage dt=0; prefetch B(0) and raw A for dt=1
    {
        float4 v0 = make_float4(0.f, 0.f, 0.f, 0.f), v1 = v0;
        if (arow_ok) {
            v0 = *(const float4*)(fptr);
            v1 = *(const float4*)(fptr + 4);
        }
        CVT_STORE(v0, v1, 0);
    }
    f16x8 bAH[4], bAL[4], bBH[4], bBL[4];
    #pragma unroll
    for (int nh = 0; nh < 4; ++nh) {
        bAH[nh] = *(const f16x8*)(bpH + nh * 512);
        bAL[nh] = *(const f16x8*)(bpL + nh * 512);
    }
    float4 pa0 = make_float4(0.f, 0.f, 0.f, 0.f), pa1 = pa0;
    float4 pb0 = pa0, pb1 = pa0;
    if (arow_ok) {
        pa0 = *(const float4*)(fptr + 32);
        pa1 = *(const float4*)(fptr + 36);
    }
    SOFT_BARRIER();

    // ---- main loop, unrolled by 2 for static prefetch register names
    for (int it2 = 0; it2 < NDT; it2 += 2) {
        BODY(it2,     bAH, bAL, bBH, bBL, pa0, pa1, pb0, pb1);
        BODY(it2 + 1, bBH, bBL, bAH, bAL, pb0, pb1, pa0, pa1);
    }
#undef BODY
#undef SOFT_BARRIER
#undef CVT_STORE

    // ---------------- epilogue: partial argmin over this block's 256 cols ----
    float cn[4];
    #pragma unroll
    for (int nh = 0; nh < 4; ++nh)
        cn[nh] = cnorm[half * 256 + wn * 64 + nh * 16 + l15];

    #pragma unroll
    for (int m = 0; m < 4; ++m) {
        #pragma unroll
        for (int r = 0; r < 4; ++r) {
            float best = cn[0] - 2.0f * acc[m][0][r];
            int   bi   = colbase;
            #pragma unroll
            for (int nh = 1; nh < 4; ++nh) {
                const int col = colbase + nh * 16;
                const float s = cn[nh] - 2.0f * acc[m][nh][r];
                if (s < best || (s == best && col < bi)) { best = s; bi = col; }
            }
            #pragma unroll
            for (int msk = 1; msk < 16; msk <<= 1) {
                const float ov = __shfl_xor(best, msk, 64);
                const int   oi = __shfl_xor(bi,   msk, 64);
                if (ov < best || (ov == best && oi < bi)) { best = ov; bi = oi; }
            }
            if (l15 == 0) {
                const int rl = m * 16 + kg * 4 + r;
                red_v[rl * 4 + wn] = best;
                red_i[rl * 4 + wn] = bi;
            }
        }
    }
    __syncthreads();

    if (tid < BM) {
        float bv = red_v[tid * 4];
        int   bi = red_i[tid * 4];
        #pragma unroll
        for (int w = 1; w < 4; ++w) {
            const float v = red_v[tid * 4 + w];
            const int   i = red_i[tid * 4 + w];
            if (v < bv || (v == bv && i < bi)) { bv = v; bi = i; }
        }
        const int r = R0 + tid;
        if (r < T) {
            pbv[(size_t)half * PB_STRIDE + r] = bv;
            pbi[(size_t)half * PB_STRIDE + r] = bi;
        }
    }
}

// ---------------- combine the two col-half partials ----------------
__global__ void combine_kernel(const float* __restrict__ pbv,
                               const int* __restrict__ pbi,
                               int* __restrict__ out, int T) {
    const int r = blockIdx.x * 256 + threadIdx.x;
    if (r < T) {
        const float s0 = pbv[r];
        const int   i0 = pbi[r];
        const float s1 = pbv[PB_STRIDE + r];
        const int   i1 = pbi[PB_STRIDE + r];
        // exact tie -> half 0 (lower index), matching numpy argmin
        out[r] = (s1 < s0) ? i1 : i0;
    }
}

extern "C" void kernel_launch(void* const* d_in, const int* in_sizes, int n_in,
                              void* d_out, int out_size, void* d_ws, size_t ws_size,
                              hipStream_t stream) {
    const float* feat = (const float*)d_in[0];
    const float* C    = (const float*)d_in[1];
    int* out          = (int*)d_out;
    const int T = in_sizes[0] / D_DIM;   // 100000
    const int K = in_sizes[1] / D_DIM;   // 500

    float*     cnorm   = (float*)d_ws;
    double*    partial = (double*)((char*)d_ws + 4096);
    _Float16*  BpH     = (_Float16*)((char*)d_ws + 131072);
    _Float16*  BpL     = (_Float16*)((char*)d_ws + 917504);
    float*     pbv     = (float*)((char*)d_ws + 1703936);
    int*       pbi     = (int*)((char*)d_ws + 2506752);

    hipLaunchKernelGGL(cnorm_partial_kernel, dim3(16), dim3(512), 0, stream,
                       C, partial, K);
    hipLaunchKernelGGL(cnorm_finish_kernel, dim3(1), dim3(512), 0, stream,
                       partial, cnorm, K);
    hipLaunchKernelGGL(packB_kernel, dim3(48), dim3(256), 0, stream,
                       C, BpH, BpL);

    const int nrb = (T + BM - 1) / BM;            // row blocks
    hipLaunchKernelGGL(assign_kernel, dim3(nrb * 2), dim3(NTH), 0, stream,
                       feat, BpH, BpL, cnorm, pbv, pbi, T);
    hipLaunchKernelGGL(combine_kernel, dim3((T + 255) / 256), dim3(256), 0, stream,
                       pbv, pbi, out, T);
}

// Round 15
// 342.537 us; speedup vs baseline: 1.8226x; 1.8226x over previous
//
#include <hip/hip_runtime.h>
#include <float.h>

#define D_DIM 768
#define K_DIM 500
#define NDT   24          // 768 / 32 D-tiles
#define BM    64          // rows per block
#define NTH   512         // 8 waves, wave wn owns cols wn*64..wn*64+63

typedef _Float16 f16x8 __attribute__((ext_vector_type(8)));
typedef _Float16 f16x4 __attribute__((ext_vector_type(4)));
typedef float    f32x4 __attribute__((ext_vector_type(4)));

// ws layout:
//   0        : cnorm   float[512]                 (2 KB)
//   4096     : partial double[16*512]             (64 KB)
//   131072   : BpH     _Float16[24*512*32]        (768 KB)
//   917504   : BpL     _Float16[24*512*32]        (768 KB)

// ---------------- cnorm prep (exact, fp64) ----------------
__global__ void cnorm_partial_kernel(const float* __restrict__ C,
                                     double* __restrict__ partial, int K) {
    const int k = threadIdx.x;
    const int w = blockIdx.x;    // 0..15
    double s = 0.0;
    if (k < K) {
        const int d0 = w * (D_DIM / 16);
        for (int d = d0; d < d0 + (D_DIM / 16); ++d) {
            const float c = C[(size_t)d * K + k];
            s = fma((double)c, (double)c, s);
        }
    }
    partial[w * 512 + k] = s;
}

__global__ void cnorm_finish_kernel(const double* __restrict__ partial,
                                    float* __restrict__ cnorm, int K) {
    const int k = threadIdx.x;
    if (k < K) {
        double s = 0.0;
        for (int w = 0; w < 16; ++w) s += partial[w * 512 + k];
        cnorm[k] = (float)s;
    } else {
        cnorm[k] = FLT_MAX;
    }
}

// ---------------- pack C into fragment-ready f16 hi/lo planes ----------------
__global__ void packB_kernel(const float* __restrict__ C,
                             _Float16* __restrict__ BpH,
                             _Float16* __restrict__ BpL) {
    const int idx = blockIdx.x * 256 + threadIdx.x;   // 0..12287
    const int col = idx & 511;
    const int dt  = idx >> 9;                         // 0..23
    f16x8 h[4], l[4];
    #pragma unroll
    for (int c = 0; c < 4; ++c)
        #pragma unroll
        for (int j = 0; j < 8; ++j) {
            const int k = c * 8 + j;
            const float v = (col < K_DIM)
                          ? C[(size_t)(dt * 32 + k) * K_DIM + col] : 0.0f;
            const _Float16 hh = (_Float16)v;
            h[c][j] = hh;
            l[c][j] = (_Float16)(v - (float)hh);
        }
    f16x8* dH = (f16x8*)(BpH + ((size_t)dt * 512 + col) * 32);
    f16x8* dL = (f16x8*)(BpL + ((size_t)dt * 512 + col) * 32);
    #pragma unroll
    for (int c = 0; c < 4; ++c) { dH[c] = h[c]; dL[c] = l[c]; }
}

// ---- main: 8-wave full-512-col fp16-split MFMA, r9 schedule, fused argmin ---
__launch_bounds__(NTH, 3)
__global__ void assign_kernel(const float* __restrict__ feat,
                              const _Float16* __restrict__ BpH,
                              const _Float16* __restrict__ BpL,
                              const float* __restrict__ cnorm,
                              int* __restrict__ out,
                              int T) {
    // A tiles double-buffered: 2 planes x 2 bufs x 4KB = 16KB (+4KB reduce)
    __shared__ __align__(16) _Float16 AsH[2][BM * 32];
    __shared__ __align__(16) _Float16 AsL[2][BM * 32];
    __shared__ float red_v[BM * 8];
    __shared__ int   red_i[BM * 8];

    const int tid  = threadIdx.x;
    const int wn   = tid >> 6;    // 0..7 (64-col slice)
    const int lane = tid & 63;
    const int l15  = lane & 15;
    const int kg   = lane >> 4;   // 0..3 (k-group)
    const int R0   = blockIdx.x * BM;

    // A staging map: 8 threads per row, one float4 each
    const int ar = tid >> 3;            // 0..63
    const int jj = tid & 7;             // 0..7 (float4 index within the row)
    const bool arow_ok = (R0 + ar) < T;
    const float* fptr = feat + (size_t)(R0 + ar) * D_DIM + jj * 4;
    const int aslot = (((jj >> 1) + (ar >> 1)) & 3);  // slot swizzle (r12 map)
    const int aoff  = ar * 32 + aslot * 8 + (jj & 1) * 4;   // f16 element offset

    // B fragment base: col = wn*64 + nh*16 + l15, k-chunk kg
    const int colbase = wn * 64 + l15;
    const _Float16* bpH = BpH + (size_t)colbase * 32 + kg * 8;
    const _Float16* bpL = BpL + (size_t)colbase * 32 + kg * 8;

    f32x4 acc[4][4];
    #pragma unroll
    for (int m = 0; m < 4; ++m)
        #pragma unroll
        for (int n = 0; n < 4; ++n) acc[m][n] = (f32x4){0.f, 0.f, 0.f, 0.f};

#define CVT_STORE(V, BUF) do {                                                 \
    const float fa_[4] = {(V).x, (V).y, (V).z, (V).w};                         \
    f16x4 h_, l_;                                                              \
    _Pragma("unroll")                                                          \
    for (int j = 0; j < 4; ++j) {                                              \
        const _Float16 hh = (_Float16)fa_[j];                                  \
        h_[j] = hh; l_[j] = (_Float16)(fa_[j] - (float)hh);                    \
    }                                                                          \
    *(f16x4*)(AsH[BUF] + aoff) = h_;                                           \
    *(f16x4*)(AsL[BUF] + aoff) = l_;                                           \
} while (0)

// lgkmcnt-only barrier: orders the LDS double-buffer across waves without
// draining vmcnt -> the raw-A register prefetch survives the barrier.
#define SOFT_BARRIER() do {                                                    \
    asm volatile("s_waitcnt lgkmcnt(0)" ::: "memory");                         \
    __builtin_amdgcn_s_barrier();                                              \
} while (0)

// One dt iteration (r9 BODY). CUR: raw A for dt+1 (consumed by CVT here);
// NXT receives raw A for dt+2.
#define BODY(DT, CUR, NXT) do {                                                \
    const int cur = (DT) & 1;                                                  \
    /* B fragments for this dt (issued first; MFMA's counted vmcnt wait */     \
    /* retires B and the OLDER A prefetch, leaving the new one in flight) */   \
    const size_t bo = (size_t)(DT) * 16384;                                    \
    f16x8 bH[4], bL[4];                                                        \
    _Pragma("unroll")                                                          \
    for (int nh = 0; nh < 4; ++nh) {                                           \
        bH[nh] = *(const f16x8*)(bpH + bo + nh * 512);                         \
        bL[nh] = *(const f16x8*)(bpL + bo + nh * 512);                         \
    }                                                                          \
    /* raw A prefetch for dt+2 (crosses the soft barrier in registers) */      \
    if ((DT) + 2 < NDT && arow_ok) {                                           \
        NXT = *(const float4*)(fptr + ((DT) + 2) * 32);                        \
    }                                                                          \
    /* A fragments from LDS buf[cur] */                                        \
    f16x8 aH[4], aL[4];                                                        \
    _Pragma("unroll")                                                          \
    for (int m = 0; m < 4; ++m) {                                              \
        const int row = m * 16 + l15;                                          \
        const int sl  = (kg + (row >> 1)) & 3;                                 \
        aH[m] = ((const f16x8*)AsH[cur])[row * 4 + sl];                        \
        aL[m] = ((const f16x8*)AsL[cur])[row * 4 + sl];                        \
    }                                                                          \
    __builtin_amdgcn_s_setprio(1);                                             \
    _Pragma("unroll")                                                          \
    for (int nh = 0; nh < 4; ++nh)                                             \
        _Pragma("unroll")                                                      \
        for (int m = 0; m < 4; ++m) {                                          \
            f32x4 a = acc[m][nh];                                              \
            a = __builtin_amdgcn_mfma_f32_16x16x32_f16(aH[m], bH[nh], a, 0, 0, 0); \
            a = __builtin_amdgcn_mfma_f32_16x16x32_f16(aL[m], bH[nh], a, 0, 0, 0); \
            a = __builtin_amdgcn_mfma_f32_16x16x32_f16(aH[m], bL[nh], a, 0, 0, 0); \
            acc[m][nh] = a;                                                    \
        }                                                                      \
    __builtin_amdgcn_s_setprio(0);                                             \
    /* stage dt+1 tile from CUR (loaded a full iteration ago -> no stall) */   \
    if ((DT) + 1 < NDT) {                                                      \
        CVT_STORE(CUR, cur ^ 1);                                               \
    }                                                                          \
    SOFT_BARRIER();                                                            \
} while (0)

    // ---- prologue: stage dt=0 synchronously; prefetch raw A for dt=1
    {
        float4 v = make_float4(0.f, 0.f, 0.f, 0.f);
        if (arow_ok) v = *(const float4*)(fptr);
        CVT_STORE(v, 0);
    }
    float4 pa = make_float4(0.f, 0.f, 0.f, 0.f), pb = pa;
    if (arow_ok) pa = *(const float4*)(fptr + 32);
    __syncthreads();

    // ---- main loop, unrolled by 2 so the prefetch regs have static names
    for (int it2 = 0; it2 < NDT; it2 += 2) {
        BODY(it2,     pa, pb);
        BODY(it2 + 1, pb, pa);
    }
#undef BODY
#undef SOFT_BARRIER
#undef CVT_STORE

    // ---------------- epilogue: full argmin over 512 cols (8 waves) ----------
    float cn[4];
    #pragma unroll
    for (int nh = 0; nh < 4; ++nh)
        cn[nh] = cnorm[wn * 64 + nh * 16 + l15];

    #pragma unroll
    for (int m = 0; m < 4; ++m) {
        #pragma unroll
        for (int r = 0; r < 4; ++r) {
            float best = cn[0] - 2.0f * acc[m][0][r];
            int   bi   = colbase;
            #pragma unroll
            for (int nh = 1; nh < 4; ++nh) {
                const int col = colbase + nh * 16;
                const float s = cn[nh] - 2.0f * acc[m][nh][r];
                if (s < best || (s == best && col < bi)) { best = s; bi = col; }
            }
            #pragma unroll
            for (int msk = 1; msk < 16; msk <<= 1) {
                const float ov = __shfl_xor(best, msk, 64);
                const int   oi = __shfl_xor(bi,   msk, 64);
                if (ov < best || (ov == best && oi < bi)) { best = ov; bi = oi; }
            }
            if (l15 == 0) {
                const int rl = m * 16 + kg * 4 + r;
                red_v[rl * 8 + wn] = best;
                red_i[rl * 8 + wn] = bi;
            }
        }
    }
    __syncthreads();

    if (tid < BM) {
        float bv = red_v[tid * 8];
        int   bi = red_i[tid * 8];
        #pragma unroll
        for (int w = 1; w < 8; ++w) {
            const float v = red_v[tid * 8 + w];
            const int   i = red_i[tid * 8 + w];
            if (v < bv || (v == bv && i < bi)) { bv = v; bi = i; }
        }
        const int r = R0 + tid;
        if (r < T) out[r] = bi;
    }
}

extern "C" void kernel_launch(void* const* d_in, const int* in_sizes, int n_in,
                              void* d_out, int out_size, void* d_ws, size_t ws_size,
                              hipStream_t stream) {
    const float* feat = (const float*)d_in[0];
    const float* C    = (const float*)d_in[1];
    int* out          = (int*)d_out;
    const int T = in_sizes[0] / D_DIM;   // 100000
    const int K = in_sizes[1] / D_DIM;   // 500

    float*     cnorm   = (float*)d_ws;
    double*    partial = (double*)((char*)d_ws + 4096);
    _Float16*  BpH     = (_Float16*)((char*)d_ws + 131072);
    _Float16*  BpL     = (_Float16*)((char*)d_ws + 917504);

    hipLaunchKernelGGL(cnorm_partial_kernel, dim3(16), dim3(512), 0, stream,
                       C, partial, K);
    hipLaunchKernelGGL(cnorm_finish_kernel, dim3(1), dim3(512), 0, stream,
                       partial, cnorm, K);
    hipLaunchKernelGGL(packB_kernel, dim3(48), dim3(256), 0, stream,
                       C, BpH, BpL);

    const int nrb = (T + BM - 1) / BM;            // row blocks
    hipLaunchKernelGGL(assign_kernel, dim3(nrb), dim3(NTH), 0, stream,
                       feat, BpH, BpL, cnorm, out, T);
}

// Round 16
// 311.750 us; speedup vs baseline: 2.0026x; 1.0988x over previous
//
#include <hip/hip_runtime.h>
#include <float.h>

#define D_DIM 768
#define K_DIM 500
#define NDT   24          // 768 / 32 D-tiles
#define BM    128         // rows per block (2x r9: amortize fixed stall)
#define NTH   256
#define PB_STRIDE 100352  // padded per-half partial stride (rows)

typedef _Float16 f16x8 __attribute__((ext_vector_type(8)));
typedef float    f32x4 __attribute__((ext_vector_type(4)));

// ws layout:
//   0        : cnorm   float[512]                 (2 KB)
//   4096     : partial double[16*512]             (64 KB)
//   131072   : BpH     _Float16[24*512*32]        (768 KB)
//   917504   : BpL     _Float16[24*512*32]        (768 KB)
//   1703936  : pbv     float[2*PB_STRIDE]         (~800 KB)
//   2506752  : pbi     int[2*PB_STRIDE]           (~800 KB)

// ---------------- cnorm prep (exact, fp64) ----------------
__global__ void cnorm_partial_kernel(const float* __restrict__ C,
                                     double* __restrict__ partial, int K) {
    const int k = threadIdx.x;
    const int w = blockIdx.x;    // 0..15
    double s = 0.0;
    if (k < K) {
        const int d0 = w * (D_DIM / 16);
        for (int d = d0; d < d0 + (D_DIM / 16); ++d) {
            const float c = C[(size_t)d * K + k];
            s = fma((double)c, (double)c, s);
        }
    }
    partial[w * 512 + k] = s;
}

__global__ void cnorm_finish_kernel(const double* __restrict__ partial,
                                    float* __restrict__ cnorm, int K) {
    const int k = threadIdx.x;
    if (k < K) {
        double s = 0.0;
        for (int w = 0; w < 16; ++w) s += partial[w * 512 + k];
        cnorm[k] = (float)s;
    } else {
        cnorm[k] = FLT_MAX;
    }
}

// ---------------- pack C into fragment-ready f16 hi/lo planes ----------------
__global__ void packB_kernel(const float* __restrict__ C,
                             _Float16* __restrict__ BpH,
                             _Float16* __restrict__ BpL) {
    const int idx = blockIdx.x * 256 + threadIdx.x;   // 0..12287
    const int col = idx & 511;
    const int dt  = idx >> 9;                         // 0..23
    f16x8 h[4], l[4];
    #pragma unroll
    for (int c = 0; c < 4; ++c)
        #pragma unroll
        for (int j = 0; j < 8; ++j) {
            const int k = c * 8 + j;
            const float v = (col < K_DIM)
                          ? C[(size_t)(dt * 32 + k) * K_DIM + col] : 0.0f;
            const _Float16 hh = (_Float16)v;
            h[c][j] = hh;
            l[c][j] = (_Float16)(v - (float)hh);
        }
    f16x8* dH = (f16x8*)(BpH + ((size_t)dt * 512 + col) * 32);
    f16x8* dL = (f16x8*)(BpL + ((size_t)dt * 512 + col) * 32);
    #pragma unroll
    for (int c = 0; c < 4; ++c) { dH[c] = h[c]; dL[c] = l[c]; }
}

// -- main: col-split fp16-split MFMA, 128x256/block, r9 schedule, 2 waves/SIMD
__launch_bounds__(NTH, 2)
__global__ void assign_kernel(const float* __restrict__ feat,
                              const _Float16* __restrict__ BpH,
                              const _Float16* __restrict__ BpL,
                              const float* __restrict__ cnorm,
                              float* __restrict__ pbv,
                              int* __restrict__ pbi,
                              int T) {
    // A tiles double-buffered: 2 planes x 2 bufs x 8KB = 32KB (+4KB reduce)
    __shared__ __align__(16) _Float16 AsH[2][BM * 32];
    __shared__ __align__(16) _Float16 AsL[2][BM * 32];
    __shared__ float red_v[BM * 4];
    __shared__ int   red_i[BM * 4];

    const int tid  = threadIdx.x;
    const int wn   = tid >> 6;    // 0..3 (64-col slice)
    const int lane = tid & 63;
    const int l15  = lane & 15;
    const int kg   = lane >> 4;   // 0..3 (k-group)
    const int bid  = blockIdx.x;
    const int half = bid & 1;     // col half: 0 -> cols 0..255, 1 -> 256..511
    const int R0   = (bid >> 1) * BM;

    // A staging map: 2 threads per row, 16 floats each (2 chunks of 8)
    const int ar = tid >> 1;            // 0..127
    const int jj = tid & 1;             // 0..1 (which 16-float half of the row)
    const bool arow_ok = (R0 + ar) < T;
    const float* fptr = feat + (size_t)(R0 + ar) * D_DIM + jj * 16;
    // this thread writes chunks c0 = 2*jj, c1 = 2*jj+1 with slot swizzle
    const int sl0 = ((2 * jj + 0) + (ar >> 1)) & 3;
    const int sl1 = ((2 * jj + 1) + (ar >> 1)) & 3;
    const int ao0 = ar * 32 + sl0 * 8;    // f16 element offsets
    const int ao1 = ar * 32 + sl1 * 8;

    // B fragment base: global col = half*256 + wn*64 + l15, k-chunk kg
    const int colbase = half * 256 + wn * 64 + l15;
    const _Float16* bpH = BpH + (size_t)colbase * 32 + kg * 8;
    const _Float16* bpL = BpL + (size_t)colbase * 32 + kg * 8;

    f32x4 acc[8][4];
    #pragma unroll
    for (int m = 0; m < 8; ++m)
        #pragma unroll
        for (int n = 0; n < 4; ++n) acc[m][n] = (f32x4){0.f, 0.f, 0.f, 0.f};

#define CVT_STORE(V0, V1, V2, V3, BUF) do {                                    \
    const float fa[16] = {(V0).x, (V0).y, (V0).z, (V0).w,                      \
                          (V1).x, (V1).y, (V1).z, (V1).w,                      \
                          (V2).x, (V2).y, (V2).z, (V2).w,                      \
                          (V3).x, (V3).y, (V3).z, (V3).w};                     \
    f16x8 h0, l0, h1, l1;                                                      \
    _Pragma("unroll")                                                          \
    for (int j = 0; j < 8; ++j) {                                              \
        const _Float16 ha = (_Float16)fa[j];                                   \
        h0[j] = ha; l0[j] = (_Float16)(fa[j] - (float)ha);                     \
        const _Float16 hb = (_Float16)fa[8 + j];                               \
        h1[j] = hb; l1[j] = (_Float16)(fa[8 + j] - (float)hb);                 \
    }                                                                          \
    *(f16x8*)(AsH[BUF] + ao0) = h0;                                            \
    *(f16x8*)(AsL[BUF] + ao0) = l0;                                            \
    *(f16x8*)(AsH[BUF] + ao1) = h1;                                            \
    *(f16x8*)(AsL[BUF] + ao1) = l1;                                            \
} while (0)

// lgkmcnt-only barrier: orders the LDS double-buffer across waves without
// draining vmcnt -> the raw-A register prefetch survives the barrier.
#define SOFT_BARRIER() do {                                                    \
    asm volatile("s_waitcnt lgkmcnt(0)" ::: "memory");                         \
    __builtin_amdgcn_s_barrier();                                              \
} while (0)

// One dt iteration (r9 BODY, 128-row wave). CUR*: raw A for dt+1 (consumed by
// CVT here); NXT* receive raw A for dt+2.
#define BODY(DT, C0, C1, C2, C3, N0, N1, N2, N3) do {                          \
    const int cur = (DT) & 1;                                                  \
    /* B fragments for this dt (issued first) */                               \
    const size_t bo = (size_t)(DT) * 16384;                                    \
    f16x8 bH[4], bL[4];                                                        \
    _Pragma("unroll")                                                          \
    for (int nh = 0; nh < 4; ++nh) {                                           \
        bH[nh] = *(const f16x8*)(bpH + bo + nh * 512);                         \
        bL[nh] = *(const f16x8*)(bpL + bo + nh * 512);                         \
    }                                                                          \
    /* raw A prefetch for dt+2 (crosses the soft barrier in registers) */      \
    if ((DT) + 2 < NDT && arow_ok) {                                           \
        const float* p = fptr + ((DT) + 2) * 32;                               \
        N0 = *(const float4*)(p);                                              \
        N1 = *(const float4*)(p + 4);                                          \
        N2 = *(const float4*)(p + 8);                                          \
        N3 = *(const float4*)(p + 12);                                         \
    }                                                                          \
    /* A frags per 2-m group (16 live frag regs) + MFMA */                     \
    _Pragma("unroll")                                                          \
    for (int mg = 0; mg < 4; ++mg) {                                           \
        f16x8 aH[2], aL[2];                                                    \
        _Pragma("unroll")                                                      \
        for (int mm = 0; mm < 2; ++mm) {                                       \
            const int row = (mg * 2 + mm) * 16 + l15;                          \
            const int sl  = (kg + (row >> 1)) & 3;                             \
            aH[mm] = ((const f16x8*)AsH[cur])[row * 4 + sl];                   \
            aL[mm] = ((const f16x8*)AsL[cur])[row * 4 + sl];                   \
        }                                                                      \
        __builtin_amdgcn_s_setprio(1);                                         \
        _Pragma("unroll")                                                      \
        for (int mm = 0; mm < 2; ++mm) {                                       \
            const int m = mg * 2 + mm;                                         \
            _Pragma("unroll")                                                  \
            for (int nh = 0; nh < 4; ++nh) {                                   \
                f32x4 a = acc[m][nh];                                          \
                a = __builtin_amdgcn_mfma_f32_16x16x32_f16(aH[mm], bH[nh], a, 0, 0, 0); \
                a = __builtin_amdgcn_mfma_f32_16x16x32_f16(aL[mm], bH[nh], a, 0, 0, 0); \
                a = __builtin_amdgcn_mfma_f32_16x16x32_f16(aH[mm], bL[nh], a, 0, 0, 0); \
                acc[m][nh] = a;                                                \
            }                                                                  \
        }                                                                      \
        __builtin_amdgcn_s_setprio(0);                                         \
    }                                                                          \
    /* stage dt+1 tile from CUR regs (loaded a full iteration ago) */          \
    if ((DT) + 1 < NDT) {                                                      \
        CVT_STORE(C0, C1, C2, C3, cur ^ 1);                                    \
    }                                                                          \
    SOFT_BARRIER();                                                            \
} while (0)

    // ---- prologue: stage dt=0 synchronously; prefetch raw A for dt=1
    {
        float4 v0 = make_float4(0.f,0.f,0.f,0.f), v1 = v0, v2 = v0, v3 = v0;
        if (arow_ok) {
            v0 = *(const float4*)(fptr);
            v1 = *(const float4*)(fptr + 4);
            v2 = *(const float4*)(fptr + 8);
            v3 = *(const float4*)(fptr + 12);
        }
        CVT_STORE(v0, v1, v2, v3, 0);
    }
    float4 pa0 = make_float4(0.f,0.f,0.f,0.f), pa1 = pa0, pa2 = pa0, pa3 = pa0;
    float4 pb0 = pa0, pb1 = pa0, pb2 = pa0, pb3 = pa0;
    if (arow_ok) {
        pa0 = *(const float4*)(fptr + 32);
        pa1 = *(const float4*)(fptr + 36);
        pa2 = *(const float4*)(fptr + 40);
        pa3 = *(const float4*)(fptr + 44);
    }
    __syncthreads();

    // ---- main loop, unrolled by 2 so the prefetch regs have static names
    for (int it2 = 0; it2 < NDT; it2 += 2) {
        BODY(it2,     pa0, pa1, pa2, pa3, pb0, pb1, pb2, pb3);
        BODY(it2 + 1, pb0, pb1, pb2, pb3, pa0, pa1, pa2, pa3);
    }
#undef BODY
#undef SOFT_BARRIER
#undef CVT_STORE

    // ---------------- epilogue: partial argmin over this block's 256 cols ----
    float cn[4];
    #pragma unroll
    for (int nh = 0; nh < 4; ++nh)
        cn[nh] = cnorm[half * 256 + wn * 64 + nh * 16 + l15];

    #pragma unroll
    for (int m = 0; m < 8; ++m) {
        #pragma unroll
        for (int r = 0; r < 4; ++r) {
            float best = cn[0] - 2.0f * acc[m][0][r];
            int   bi   = colbase;
            #pragma unroll
            for (int nh = 1; nh < 4; ++nh) {
                const int col = colbase + nh * 16;
                const float s = cn[nh] - 2.0f * acc[m][nh][r];
                if (s < best || (s == best && col < bi)) { best = s; bi = col; }
            }
            #pragma unroll
            for (int msk = 1; msk < 16; msk <<= 1) {
                const float ov = __shfl_xor(best, msk, 64);
                const int   oi = __shfl_xor(bi,   msk, 64);
                if (ov < best || (ov == best && oi < bi)) { best = ov; bi = oi; }
            }
            if (l15 == 0) {
                const int rl = m * 16 + kg * 4 + r;
                red_v[rl * 4 + wn] = best;
                red_i[rl * 4 + wn] = bi;
            }
        }
    }
    __syncthreads();

    if (tid < BM) {
        float bv = red_v[tid * 4];
        int   bi = red_i[tid * 4];
        #pragma unroll
        for (int w = 1; w < 4; ++w) {
            const float v = red_v[tid * 4 + w];
            const int   i = red_i[tid * 4 + w];
            if (v < bv || (v == bv && i < bi)) { bv = v; bi = i; }
        }
        const int r = R0 + tid;
        if (r < T) {
            pbv[(size_t)half * PB_STRIDE + r] = bv;
            pbi[(size_t)half * PB_STRIDE + r] = bi;
        }
    }
}

// ---------------- combine the two col-half partials ----------------
__global__ void combine_kernel(const float* __restrict__ pbv,
                               const int* __restrict__ pbi,
                               int* __restrict__ out, int T) {
    const int r = blockIdx.x * 256 + threadIdx.x;
    if (r < T) {
        const float s0 = pbv[r];
        const int   i0 = pbi[r];
        const float s1 = pbv[PB_STRIDE + r];
        const int   i1 = pbi[PB_STRIDE + r];
        // exact tie -> half 0 (lower index), matching numpy argmin
        out[r] = (s1 < s0) ? i1 : i0;
    }
}

extern "C" void kernel_launch(void* const* d_in, const int* in_sizes, int n_in,
                              void* d_out, int out_size, void* d_ws, size_t ws_size,
                              hipStream_t stream) {
    const float* feat = (const float*)d_in[0];
    const float* C    = (const float*)d_in[1];
    int* out          = (int*)d_out;
    const int T = in_sizes[0] / D_DIM;   // 100000
    const int K = in_sizes[1] / D_DIM;   // 500

    float*     cnorm   = (float*)d_ws;
    double*    partial = (double*)((char*)d_ws + 4096);
    _Float16*  BpH     = (_Float16*)((char*)d_ws + 131072);
    _Float16*  BpL     = (_Float16*)((char*)d_ws + 917504);
    float*     pbv     = (float*)((char*)d_ws + 1703936);
    int*       pbi     = (int*)((char*)d_ws + 2506752);

    hipLaunchKernelGGL(cnorm_partial_kernel, dim3(16), dim3(512), 0, stream,
                       C, partial, K);
    hipLaunchKernelGGL(cnorm_finish_kernel, dim3(1), dim3(512), 0, stream,
                       partial, cnorm, K);
    hipLaunchKernelGGL(packB_kernel, dim3(48), dim3(256), 0, stream,
                       C, BpH, BpL);

    const int nrb = (T + BM - 1) / BM;            // row blocks
    hipLaunchKernelGGL(assign_kernel, dim3(nrb * 2), dim3(NTH), 0, stream,
                       feat, BpH, BpL, cnorm, pbv, pbi, T);
    hipLaunchKernelGGL(combine_kernel, dim3((T + 255) / 256), dim3(256), 0, stream,
                       pbv, pbi, out, T);
}

// Round 17
// 266.163 us; speedup vs baseline: 2.3456x; 1.1713x over previous
//
#include <hip/hip_runtime.h>
#include <float.h>

#define D_DIM 768
#define K_DIM 500
#define NDT   24          // 768 / 32 D-tiles
#define BM    64          // rows per block
#define NTH   256
#define PB_STRIDE 100352  // padded per-half partial stride (rows)
#define BLOFF 393216      // (BpL - BpH) in f16 elements (768 KB / 2)

typedef _Float16 f16x8 __attribute__((ext_vector_type(8)));
typedef float    f32x4 __attribute__((ext_vector_type(4)));

// ws layout:
//   0        : cnorm   float[512]                 (2 KB)
//   4096     : partial double[16*512]             (64 KB)
//   131072   : BpH     _Float16[24*512*32]        (768 KB)
//   917504   : BpL     _Float16[24*512*32]        (768 KB)   (BpH + BLOFF elems)
//   1703936  : pbv     float[2*PB_STRIDE]         (~800 KB)
//   2506752  : pbi     int[2*PB_STRIDE]           (~800 KB)

// ---------------- cnorm prep (exact, fp64) ----------------
__global__ void cnorm_partial_kernel(const float* __restrict__ C,
                                     double* __restrict__ partial, int K) {
    const int k = threadIdx.x;
    const int w = blockIdx.x;    // 0..15
    double s = 0.0;
    if (k < K) {
        const int d0 = w * (D_DIM / 16);
        for (int d = d0; d < d0 + (D_DIM / 16); ++d) {
            const float c = C[(size_t)d * K + k];
            s = fma((double)c, (double)c, s);
        }
    }
    partial[w * 512 + k] = s;
}

__global__ void cnorm_finish_kernel(const double* __restrict__ partial,
                                    float* __restrict__ cnorm, int K) {
    const int k = threadIdx.x;
    if (k < K) {
        double s = 0.0;
        for (int w = 0; w < 16; ++w) s += partial[w * 512 + k];
        cnorm[k] = (float)s;
    } else {
        cnorm[k] = FLT_MAX;
    }
}

// ---------------- pack C into fragment-ready f16 hi/lo planes ----------------
__global__ void packB_kernel(const float* __restrict__ C,
                             _Float16* __restrict__ BpH,
                             _Float16* __restrict__ BpL) {
    const int idx = blockIdx.x * 256 + threadIdx.x;   // 0..12287
    const int col = idx & 511;
    const int dt  = idx >> 9;                         // 0..23
    f16x8 h[4], l[4];
    #pragma unroll
    for (int c = 0; c < 4; ++c)
        #pragma unroll
        for (int j = 0; j < 8; ++j) {
            const int k = c * 8 + j;
            const float v = (col < K_DIM)
                          ? C[(size_t)(dt * 32 + k) * K_DIM + col] : 0.0f;
            const _Float16 hh = (_Float16)v;
            h[c][j] = hh;
            l[c][j] = (_Float16)(v - (float)hh);
        }
    f16x8* dH = (f16x8*)(BpH + ((size_t)dt * 512 + col) * 32);
    f16x8* dL = (f16x8*)(BpL + ((size_t)dt * 512 + col) * 32);
    #pragma unroll
    for (int c = 0; c < 4; ++c) { dH[c] = h[c]; dL[c] = l[c]; }
}

// -- main: col-split fp16-split MFMA (r9 schedule), register diet, 4 waves/SIMD
__launch_bounds__(NTH, 4)
__global__ void assign_kernel(const float* __restrict__ feat,
                              const _Float16* __restrict__ BpH,
                              const float* __restrict__ cnorm,
                              float* __restrict__ pbv,
                              int* __restrict__ pbi,
                              int T) {
    // A tiles double-buffered: 2 planes x 2 bufs x 4KB = 16KB (+4KB reduce)
    __shared__ __align__(16) _Float16 AsH[2][BM * 32];
    __shared__ __align__(16) _Float16 AsL[2][BM * 32];
    __shared__ float red_v[BM * 4];
    __shared__ int   red_i[BM * 4];

    const int tid  = threadIdx.x;
    const int wn   = tid >> 6;    // 0..3 (64-col slice)
    const int lane = tid & 63;
    const int l15  = lane & 15;
    const int kg   = lane >> 4;   // 0..3 (k-group)
    const int bid  = blockIdx.x;
    const int half = bid & 1;     // col half: 0 -> cols 0..255, 1 -> 256..511
    const int R0   = (bid >> 1) * BM;

    // A staging map: 4 threads per row, 8 floats each
    const int ar = tid >> 2;            // 0..63
    const int ac = (tid & 3) << 3;      // 0,8,16,24
    const bool arow_ok = (R0 + ar) < T;
    const float* fptr = feat + (size_t)(R0 + ar) * D_DIM + ac;
    const int asl = ((ac >> 3) + (ar >> 1)) & 3;      // slot swizzle for write

    // B fragment base: global col = half*256 + wn*64 + l15, k-chunk kg.
    // Lo plane at fixed +BLOFF from hi plane (saves one pointer pair).
    const _Float16* bp = BpH + (size_t)(half * 256 + wn * 64 + l15) * 32 + kg * 8;

    f32x4 acc[4][4];
    #pragma unroll
    for (int m = 0; m < 4; ++m)
        #pragma unroll
        for (int n = 0; n < 4; ++n) acc[m][n] = (f32x4){0.f, 0.f, 0.f, 0.f};

#define CVT_STORE(V0, V1, BUF) do {                                            \
    const float fa[8] = {(V0).x, (V0).y, (V0).z, (V0).w,                       \
                         (V1).x, (V1).y, (V1).z, (V1).w};                      \
    f16x8 h, l;                                                                \
    _Pragma("unroll")                                                          \
    for (int j = 0; j < 8; ++j) {                                              \
        const _Float16 hh = (_Float16)fa[j];                                   \
        h[j] = hh; l[j] = (_Float16)(fa[j] - (float)hh);                       \
    }                                                                          \
    ((f16x8*)AsH[BUF])[ar * 4 + asl] = h;                                      \
    ((f16x8*)AsL[BUF])[ar * 4 + asl] = l;                                      \
} while (0)

// lgkmcnt-only barrier: orders the LDS double-buffer across waves without
// draining vmcnt -> register prefetches survive the barrier.
#define SOFT_BARRIER() do {                                                    \
    asm volatile("s_waitcnt lgkmcnt(0)" ::: "memory");                         \
    __builtin_amdgcn_s_barrier();                                              \
} while (0)

    // ---- prologue: stage dt=0 synchronously
    {
        float4 v0 = make_float4(0.f, 0.f, 0.f, 0.f), v1 = v0;
        if (arow_ok) {
            v0 = *(const float4*)(fptr);
            v1 = *(const float4*)(fptr + 4);
        }
        CVT_STORE(v0, v1, 0);
    }
    __syncthreads();

    // ---- main loop (r6-style depth-1 A prefetch, r9 B-first ordering)
    #pragma unroll 1
    for (int dt = 0; dt < NDT; ++dt) {
        const int cur = dt & 1;
        const bool hasNext = (dt + 1) < NDT;

        // B fragments for this dt (issued first)
        const size_t bo = (size_t)dt * 16384;
        f16x8 bH[4], bL[4];
        #pragma unroll
        for (int nh = 0; nh < 4; ++nh) {
            bH[nh] = *(const f16x8*)(bp + bo + nh * 512);
            bL[nh] = *(const f16x8*)(bp + BLOFF + bo + nh * 512);
        }

        // raw A for dt+1 (issued after B; consumed by CVT at iteration end)
        float4 v0 = make_float4(0.f, 0.f, 0.f, 0.f), v1 = v0;
        if (hasNext && arow_ok) {
            v0 = *(const float4*)(fptr + (dt + 1) * 32);
            v1 = *(const float4*)(fptr + (dt + 1) * 32 + 4);
        }

        // A frags per 2-m group (16 live frag regs) + MFMA
        #pragma unroll
        for (int mg = 0; mg < 2; ++mg) {
            f16x8 aH[2], aL[2];
            #pragma unroll
            for (int mm = 0; mm < 2; ++mm) {
                const int row = (mg * 2 + mm) * 16 + l15;
                const int sl  = (kg + (row >> 1)) & 3;
                aH[mm] = ((const f16x8*)AsH[cur])[row * 4 + sl];
                aL[mm] = ((const f16x8*)AsL[cur])[row * 4 + sl];
            }
            __builtin_amdgcn_s_setprio(1);
            #pragma unroll
            for (int mm = 0; mm < 2; ++mm) {
                const int m = mg * 2 + mm;
                #pragma unroll
                for (int nh = 0; nh < 4; ++nh) {
                    f32x4 a = acc[m][nh];
                    a = __builtin_amdgcn_mfma_f32_16x16x32_f16(aH[mm], bH[nh], a, 0, 0, 0);
                    a = __builtin_amdgcn_mfma_f32_16x16x32_f16(aL[mm], bH[nh], a, 0, 0, 0);
                    a = __builtin_amdgcn_mfma_f32_16x16x32_f16(aH[mm], bL[nh], a, 0, 0, 0);
                    acc[m][nh] = a;
                }
            }
            __builtin_amdgcn_s_setprio(0);
        }

        // stage dt+1 tile into buf[cur^1]
        if (hasNext) {
            CVT_STORE(v0, v1, cur ^ 1);
        }
        SOFT_BARRIER();
    }
#undef SOFT_BARRIER
#undef CVT_STORE

    // ---------------- epilogue: partial argmin over this block's 256 cols ----
    const int colbase = half * 256 + wn * 64 + l15;
    float cn[4];
    #pragma unroll
    for (int nh = 0; nh < 4; ++nh)
        cn[nh] = cnorm[colbase + nh * 16];

    #pragma unroll
    for (int m = 0; m < 4; ++m) {
        #pragma unroll
        for (int r = 0; r < 4; ++r) {
            float best = cn[0] - 2.0f * acc[m][0][r];
            int   bi   = colbase;
            #pragma unroll
            for (int nh = 1; nh < 4; ++nh) {
                const int col = colbase + nh * 16;
                const float s = cn[nh] - 2.0f * acc[m][nh][r];
                if (s < best || (s == best && col < bi)) { best = s; bi = col; }
            }
            #pragma unroll
            for (int msk = 1; msk < 16; msk <<= 1) {
                const float ov = __shfl_xor(best, msk, 64);
                const int   oi = __shfl_xor(bi,   msk, 64);
                if (ov < best || (ov == best && oi < bi)) { best = ov; bi = oi; }
            }
            if (l15 == 0) {
                const int rl = m * 16 + kg * 4 + r;
                red_v[rl * 4 + wn] = best;
                red_i[rl * 4 + wn] = bi;
            }
        }
    }
    __syncthreads();

    if (tid < BM) {
        float bv = red_v[tid * 4];
        int   bi = red_i[tid * 4];
        #pragma unroll
        for (int w = 1; w < 4; ++w) {
            const float v = red_v[tid * 4 + w];
            const int   i = red_i[tid * 4 + w];
            if (v < bv || (v == bv && i < bi)) { bv = v; bi = i; }
        }
        const int r = R0 + tid;
        if (r < T) {
            pbv[(size_t)half * PB_STRIDE + r] = bv;
            pbi[(size_t)half * PB_STRIDE + r] = bi;
        }
    }
}

// ---------------- combine the two col-half partials ----------------
__global__ void combine_kernel(const float* __restrict__ pbv,
                               const int* __restrict__ pbi,
                               int* __restrict__ out, int T) {
    const int r = blockIdx.x * 256 + threadIdx.x;
    if (r < T) {
        const float s0 = pbv[r];
        const int   i0 = pbi[r];
        const float s1 = pbv[PB_STRIDE + r];
        const int   i1 = pbi[PB_STRIDE + r];
        // exact tie -> half 0 (lower index), matching numpy argmin
        out[r] = (s1 < s0) ? i1 : i0;
    }
}

extern "C" void kernel_launch(void* const* d_in, const int* in_sizes, int n_in,
                              void* d_out, int out_size, void* d_ws, size_t ws_size,
                              hipStream_t stream) {
    const float* feat = (const float*)d_in[0];
    const float* C    = (const float*)d_in[1];
    int* out          = (int*)d_out;
    const int T = in_sizes[0] / D_DIM;   // 100000
    const int K = in_sizes[1] / D_DIM;   // 500

    float*     cnorm   = (float*)d_ws;
    double*    partial = (double*)((char*)d_ws + 4096);
    _Float16*  BpH     = (_Float16*)((char*)d_ws + 131072);
    _Float16*  BpL     = (_Float16*)((char*)d_ws + 917504);
    float*     pbv     = (float*)((char*)d_ws + 1703936);
    int*       pbi     = (int*)((char*)d_ws + 2506752);

    hipLaunchKernelGGL(cnorm_partial_kernel, dim3(16), dim3(512), 0, stream,
                       C, partial, K);
    hipLaunchKernelGGL(cnorm_finish_kernel, dim3(1), dim3(512), 0, stream,
                       partial, cnorm, K);
    hipLaunchKernelGGL(packB_kernel, dim3(48), dim3(256), 0, stream,
                       C, BpH, BpL);

    const int nrb = (T + BM - 1) / BM;            // row blocks
    hipLaunchKernelGGL(assign_kernel, dim3(nrb * 2), dim3(NTH), 0, stream,
                       feat, BpH, cnorm, pbv, pbi, T);
    hipLaunchKernelGGL(combine_kernel, dim3((T + 255) / 256), dim3(256), 0, stream,
                       pbv, pbi, out, T);
}

// Round 18
// 265.987 us; speedup vs baseline: 2.3472x; 1.0007x over previous
//
#include <hip/hip_runtime.h>
#include <float.h>

#define D_DIM 768
#define K_DIM 500
#define NDT   24          // 768 / 32 D-tiles
#define BM    64          // rows per block
#define NTH   256
#define PB_STRIDE 100352  // padded per-half partial stride (rows)
#define BLOFF 393216      // (BpL - BpH) in f16 elements (768 KB / 2)

typedef _Float16 f16x8 __attribute__((ext_vector_type(8)));
typedef float    f32x4 __attribute__((ext_vector_type(4)));

// ws layout:
//   0        : cnorm   float[512]                 (2 KB)
//   4096     : partial double[16*512]             (64 KB)
//   131072   : BpH     _Float16[24*512*32]        (768 KB)
//   917504   : BpL     _Float16[24*512*32]        (768 KB)   (BpH + BLOFF elems)
//   1703936  : pbv     float[2*PB_STRIDE]         (~800 KB)
//   2506752  : pbi     int[2*PB_STRIDE]           (~800 KB)

// ---------------- cnorm prep (exact, fp64) ----------------
__global__ void cnorm_partial_kernel(const float* __restrict__ C,
                                     double* __restrict__ partial, int K) {
    const int k = threadIdx.x;
    const int w = blockIdx.x;    // 0..15
    double s = 0.0;
    if (k < K) {
        const int d0 = w * (D_DIM / 16);
        for (int d = d0; d < d0 + (D_DIM / 16); ++d) {
            const float c = C[(size_t)d * K + k];
            s = fma((double)c, (double)c, s);
        }
    }
    partial[w * 512 + k] = s;
}

__global__ void cnorm_finish_kernel(const double* __restrict__ partial,
                                    float* __restrict__ cnorm, int K) {
    const int k = threadIdx.x;
    if (k < K) {
        double s = 0.0;
        for (int w = 0; w < 16; ++w) s += partial[w * 512 + k];
        cnorm[k] = (float)s;
    } else {
        cnorm[k] = FLT_MAX;
    }
}

// ---------------- pack C into fragment-ready f16 hi/lo planes ----------------
__global__ void packB_kernel(const float* __restrict__ C,
                             _Float16* __restrict__ BpH,
                             _Float16* __restrict__ BpL) {
    const int idx = blockIdx.x * 256 + threadIdx.x;   // 0..12287
    const int col = idx & 511;
    const int dt  = idx >> 9;                         // 0..23
    f16x8 h[4], l[4];
    #pragma unroll
    for (int c = 0; c < 4; ++c)
        #pragma unroll
        for (int j = 0; j < 8; ++j) {
            const int k = c * 8 + j;
            const float v = (col < K_DIM)
                          ? C[(size_t)(dt * 32 + k) * K_DIM + col] : 0.0f;
            const _Float16 hh = (_Float16)v;
            h[c][j] = hh;
            l[c][j] = (_Float16)(v - (float)hh);
        }
    f16x8* dH = (f16x8*)(BpH + ((size_t)dt * 512 + col) * 32);
    f16x8* dL = (f16x8*)(BpL + ((size_t)dt * 512 + col) * 32);
    #pragma unroll
    for (int c = 0; c < 4; ++c) { dH[c] = h[c]; dL[c] = l[c]; }
}

// -- main: col-split fp16-split MFMA, 4-buf LDS rotation, barrier every 2 dt --
__launch_bounds__(NTH, 4)
__global__ void assign_kernel(const float* __restrict__ feat,
                              const _Float16* __restrict__ BpH,
                              const float* __restrict__ cnorm,
                              float* __restrict__ pbv,
                              int* __restrict__ pbi,
                              int T) {
    // A tiles: 4-buffer rotation, 2 planes x 4 bufs x 4KB = 32KB (+4KB reduce)
    __shared__ __align__(16) _Float16 AsH[4][BM * 32];
    __shared__ __align__(16) _Float16 AsL[4][BM * 32];
    __shared__ float red_v[BM * 4];
    __shared__ int   red_i[BM * 4];

    const int tid  = threadIdx.x;
    const int wn   = tid >> 6;    // 0..3 (64-col slice)
    const int lane = tid & 63;
    const int l15  = lane & 15;
    const int kg   = lane >> 4;   // 0..3 (k-group)
    const int bid  = blockIdx.x;
    const int half = bid & 1;     // col half: 0 -> cols 0..255, 1 -> 256..511
    const int R0   = (bid >> 1) * BM;

    // A staging map: 4 threads per row, 8 floats each
    const int ar = tid >> 2;            // 0..63
    const int ac = (tid & 3) << 3;      // 0,8,16,24
    const bool arow_ok = (R0 + ar) < T;
    const float* fptr = feat + (size_t)(R0 + ar) * D_DIM + ac;
    const int asl = ((ac >> 3) + (ar >> 1)) & 3;      // slot swizzle for write

    // B fragment base: global col = half*256 + wn*64 + l15, k-chunk kg.
    const _Float16* bp = BpH + (size_t)(half * 256 + wn * 64 + l15) * 32 + kg * 8;

    f32x4 acc[4][4];
    #pragma unroll
    for (int m = 0; m < 4; ++m)
        #pragma unroll
        for (int n = 0; n < 4; ++n) acc[m][n] = (f32x4){0.f, 0.f, 0.f, 0.f};

#define CVT_STORE(V0, V1, BUF) do {                                            \
    const float fa[8] = {(V0).x, (V0).y, (V0).z, (V0).w,                       \
                         (V1).x, (V1).y, (V1).z, (V1).w};                      \
    f16x8 h, l;                                                                \
    _Pragma("unroll")                                                          \
    for (int j = 0; j < 8; ++j) {                                              \
        const _Float16 hh = (_Float16)fa[j];                                   \
        h[j] = hh; l[j] = (_Float16)(fa[j] - (float)hh);                       \
    }                                                                          \
    ((f16x8*)AsH[BUF])[ar * 4 + asl] = h;                                      \
    ((f16x8*)AsL[BUF])[ar * 4 + asl] = l;                                      \
} while (0)

// lgkmcnt-only barrier: orders the LDS buffer rotation across waves without
// draining vmcnt -> register prefetches survive the barrier.
#define SOFT_BARRIER() do {                                                    \
    asm volatile("s_waitcnt lgkmcnt(0)" ::: "memory");                         \
    __builtin_amdgcn_s_barrier();                                              \
} while (0)

    // ---- prologue: stage dt=0 and dt=1 synchronously
    {
        float4 v0 = make_float4(0.f, 0.f, 0.f, 0.f), v1 = v0, v2 = v0, v3 = v0;
        if (arow_ok) {
            v0 = *(const float4*)(fptr);
            v1 = *(const float4*)(fptr + 4);
            v2 = *(const float4*)(fptr + 32);
            v3 = *(const float4*)(fptr + 36);
        }
        CVT_STORE(v0, v1, 0);
        CVT_STORE(v2, v3, 1);
    }
    __syncthreads();

    // ---- main loop: buf (dt&3) consumed, buf ((dt+2)&3) staged,
    //      barrier only after odd dt (all 4 bufs distinct within the window)
    #pragma unroll 1
    for (int dt = 0; dt < NDT; ++dt) {
        const int cur = dt & 3;
        const bool hasStage = (dt + 2) < NDT;

        // B fragments for this dt (issued first)
        const size_t bo = (size_t)dt * 16384;
        f16x8 bH[4], bL[4];
        #pragma unroll
        for (int nh = 0; nh < 4; ++nh) {
            bH[nh] = *(const f16x8*)(bp + bo + nh * 512);
            bL[nh] = *(const f16x8*)(bp + BLOFF + bo + nh * 512);
        }

        // raw A for dt+2 (issued after B; consumed by CVT at iteration end)
        float4 v0 = make_float4(0.f, 0.f, 0.f, 0.f), v1 = v0;
        if (hasStage && arow_ok) {
            v0 = *(const float4*)(fptr + (dt + 2) * 32);
            v1 = *(const float4*)(fptr + (dt + 2) * 32 + 4);
        }

        // A frags per 2-m group (16 live frag regs) + MFMA
        #pragma unroll
        for (int mg = 0; mg < 2; ++mg) {
            f16x8 aH[2], aL[2];
            #pragma unroll
            for (int mm = 0; mm < 2; ++mm) {
                const int row = (mg * 2 + mm) * 16 + l15;
                const int sl  = (kg + (row >> 1)) & 3;
                aH[mm] = ((const f16x8*)AsH[cur])[row * 4 + sl];
                aL[mm] = ((const f16x8*)AsL[cur])[row * 4 + sl];
            }
            #pragma unroll
            for (int mm = 0; mm < 2; ++mm) {
                const int m = mg * 2 + mm;
                #pragma unroll
                for (int nh = 0; nh < 4; ++nh) {
                    f32x4 a = acc[m][nh];
                    a = __builtin_amdgcn_mfma_f32_16x16x32_f16(aH[mm], bH[nh], a, 0, 0, 0);
                    a = __builtin_amdgcn_mfma_f32_16x16x32_f16(aL[mm], bH[nh], a, 0, 0, 0);
                    a = __builtin_amdgcn_mfma_f32_16x16x32_f16(aH[mm], bL[nh], a, 0, 0, 0);
                    acc[m][nh] = a;
                }
            }
        }

        // stage dt+2 tile into buf[(dt+2)&3]
        if (hasStage) {
            CVT_STORE(v0, v1, (dt + 2) & 3);
        }
        // barrier only at the end of odd iterations
        if (dt & 1) SOFT_BARRIER();
    }
#undef SOFT_BARRIER
#undef CVT_STORE

    // ---------------- epilogue: partial argmin over this block's 256 cols ----
    const int colbase = half * 256 + wn * 64 + l15;
    float cn[4];
    #pragma unroll
    for (int nh = 0; nh < 4; ++nh)
        cn[nh] = cnorm[colbase + nh * 16];

    #pragma unroll
    for (int m = 0; m < 4; ++m) {
        #pragma unroll
        for (int r = 0; r < 4; ++r) {
            float best = cn[0] - 2.0f * acc[m][0][r];
            int   bi   = colbase;
            #pragma unroll
            for (int nh = 1; nh < 4; ++nh) {
                const int col = colbase + nh * 16;
                const float s = cn[nh] - 2.0f * acc[m][nh][r];
                if (s < best || (s == best && col < bi)) { best = s; bi = col; }
            }
            #pragma unroll
            for (int msk = 1; msk < 16; msk <<= 1) {
                const float ov = __shfl_xor(best, msk, 64);
                const int   oi = __shfl_xor(bi,   msk, 64);
                if (ov < best || (ov == best && oi < bi)) { best = ov; bi = oi; }
            }
            if (l15 == 0) {
                const int rl = m * 16 + kg * 4 + r;
                red_v[rl * 4 + wn] = best;
                red_i[rl * 4 + wn] = bi;
            }
        }
    }
    __syncthreads();

    if (tid < BM) {
        float bv = red_v[tid * 4];
        int   bi = red_i[tid * 4];
        #pragma unroll
        for (int w = 1; w < 4; ++w) {
            const float v = red_v[tid * 4 + w];
            const int   i = red_i[tid * 4 + w];
            if (v < bv || (v == bv && i < bi)) { bv = v; bi = i; }
        }
        const int r = R0 + tid;
        if (r < T) {
            pbv[(size_t)half * PB_STRIDE + r] = bv;
            pbi[(size_t)half * PB_STRIDE + r] = bi;
        }
    }
}

// ---------------- combine the two col-half partials ----------------
__global__ void combine_kernel(const float* __restrict__ pbv,
                               const int* __restrict__ pbi,
                               int* __restrict__ out, int T) {
    const int r = blockIdx.x * 256 + threadIdx.x;
    if (r < T) {
        const float s0 = pbv[r];
        const int   i0 = pbi[r];
        const float s1 = pbv[PB_STRIDE + r];
        const int   i1 = pbi[PB_STRIDE + r];
        // exact tie -> half 0 (lower index), matching numpy argmin
        out[r] = (s1 < s0) ? i1 : i0;
    }
}

extern "C" void kernel_launch(void* const* d_in, const int* in_sizes, int n_in,
                              void* d_out, int out_size, void* d_ws, size_t ws_size,
                              hipStream_t stream) {
    const float* feat = (const float*)d_in[0];
    const float* C    = (const float*)d_in[1];
    int* out          = (int*)d_out;
    const int T = in_sizes[0] / D_DIM;   // 100000
    const int K = in_sizes[1] / D_DIM;   // 500

    float*     cnorm   = (float*)d_ws;
    double*    partial = (double*)((char*)d_ws + 4096);
    _Float16*  BpH     = (_Float16*)((char*)d_ws + 131072);
    _Float16*  BpL     = (_Float16*)((char*)d_ws + 917504);
    float*     pbv     = (float*)((char*)d_ws + 1703936);
    int*       pbi     = (int*)((char*)d_ws + 2506752);

    hipLaunchKernelGGL(cnorm_partial_kernel, dim3(16), dim3(512), 0, stream,
                       C, partial, K);
    hipLaunchKernelGGL(cnorm_finish_kernel, dim3(1), dim3(512), 0, stream,
                       partial, cnorm, K);
    hipLaunchKernelGGL(packB_kernel, dim3(48), dim3(256), 0, stream,
                       C, BpH, BpL);

    const int nrb = (T + BM - 1) / BM;            // row blocks
    hipLaunchKernelGGL(assign_kernel, dim3(nrb * 2), dim3(NTH), 0, stream,
                       feat, BpH, cnorm, pbv, pbi, T);
    hipLaunchKernelGGL(combine_kernel, dim3((T + 255) / 256), dim3(256), 0, stream,
                       pbv, pbi, out, T);
}